// Round 2
// baseline (327.051 us; speedup 1.0000x reference)
//
#include <hip/hip_runtime.h>

typedef unsigned short u16;
typedef unsigned int u32;
typedef __bf16 bf16x8 __attribute__((ext_vector_type(8)));
typedef float f32x4 __attribute__((ext_vector_type(4)));
typedef u16 u16x4 __attribute__((ext_vector_type(4)));
typedef u16 u16x8 __attribute__((ext_vector_type(8)));

#define MFMA16x16x32(a, b, c) __builtin_amdgcn_mfma_f32_16x16x32_bf16((a), (b), (c), 0, 0, 0)

static constexpr int kB = 4;
static constexpr int kC = 256;
static constexpr int kN = 4096;     // H*W
static constexpr int kHeads = 4;    // per batch
static constexpr int kD = 64;       // head dim
static constexpr int kSplit = 4;    // attn is reg-capped, not grid-capped; 4 halves combine traffic
static constexpr float kScale = 0.35355339059327373f;   // 64^-0.25 (K side)
static constexpr float kScaleQ = 0.51006971545f;        // 64^-0.25 * log2(e) (Q side, r15: exp->exp2)

__device__ __forceinline__ u16 f2bf(float f) {
  union { float f; u32 i; } v; v.f = f;
  return (u16)((v.i + 0x7fffu + ((v.i >> 16) & 1u)) >> 16);
}
__device__ __forceinline__ bf16x8 ldb8(const u16* p) {
  return *reinterpret_cast<const bf16x8*>(p);
}

// ---------------------------------------------------------------------------
// fp32 -> bf16 weight conversion (grid-stride).
// ---------------------------------------------------------------------------
__global__ void convert_bf16(const float* __restrict__ in, u16* __restrict__ out,
                             int n) {
  for (int i = blockIdx.x * blockDim.x + threadIdx.x; i < n;
       i += gridDim.x * blockDim.x)
    out[i] = f2bf(in[i]);
}

// ---------------------------------------------------------------------------
// GroupNorm (validated r4). Writes bf16 transposed xnT[b][t][c].
// ---------------------------------------------------------------------------
__global__ __launch_bounds__(1024) void gn_kernel(const float* __restrict__ x,
                                                  const float* __restrict__ gnw,
                                                  const float* __restrict__ gnb,
                                                  u16* __restrict__ xnT) {
  const int g = blockIdx.x, b = blockIdx.y;
  const int tid = threadIdx.x;
  const float* xb = x + b * (kC * kN) + g * 8 * kN;
  float vals[4][8];
  float s = 0.f, ss = 0.f;
#pragma unroll
  for (int kk = 0; kk < 4; ++kk) {
    const int t = tid + kk * 1024;
#pragma unroll
    for (int c = 0; c < 8; ++c) {
      const float v_ = xb[c * kN + t];
      vals[kk][c] = v_;
      s += v_; ss += v_ * v_;
    }
  }
#pragma unroll
  for (int off = 32; off > 0; off >>= 1) {
    s += __shfl_down(s, off);
    ss += __shfl_down(ss, off);
  }
  __shared__ float rbuf[32];
  const int wid = tid >> 6, lane = tid & 63;
  if (lane == 0) { rbuf[wid] = s; rbuf[16 + wid] = ss; }
  __syncthreads();
  if (tid < 64) {
    float s2 = (lane < 16) ? rbuf[lane] : 0.f;
    float ss2 = (lane < 16) ? rbuf[16 + lane] : 0.f;
#pragma unroll
    for (int off = 8; off > 0; off >>= 1) {
      s2 += __shfl_down(s2, off);
      ss2 += __shfl_down(ss2, off);
    }
    if (lane == 0) { rbuf[0] = s2; rbuf[1] = ss2; }
  }
  __syncthreads();
  const float inv_n = 1.f / 32768.f;
  const float mu = rbuf[0] * inv_n;
  const float var = rbuf[1] * inv_n - mu * mu;
  const float rs = rsqrtf(var + 1e-5f);
  float wv[8], bv[8];
#pragma unroll
  for (int c = 0; c < 8; ++c) {
    const float wgt = gnw[g * 8 + c] * rs;
    wv[c] = wgt;
    bv[c] = gnb[g * 8 + c] - mu * wgt;
  }
  u16* ob = xnT + b * (kN * kC) + g * 8;
#pragma unroll
  for (int kk = 0; kk < 4; ++kk) {
    const int t = tid + kk * 1024;
    u16x8 pk;
#pragma unroll
    for (int c = 0; c < 8; ++c) pk[c] = f2bf(vals[kk][c] * wv[c] + bv[c]);
    *reinterpret_cast<u16x8*>(ob + t * kC) = pk;
  }
}

// ---------------------------------------------------------------------------
// QKV GEMM (validated r4). Epilogue: qT/kT[bh][t][64] pre-scaled.
// r14: V stored PERMUTED within each 32-column block: stored index
// 2c <-> s=c, 2c+1 <-> s=c+16. Matches attn's packed-P LDS ordering
// (MFMA k-order is summation order -> exact as long as P and V agree).
// r15: Q side additionally folds log2(e) so attn uses exp2 directly.
// ---------------------------------------------------------------------------
__global__ __launch_bounds__(256) void qkv_gemm(const u16* __restrict__ qkvw,
                                                const float* __restrict__ qkvb,
                                                const u16* __restrict__ xnT,
                                                u16* __restrict__ qt,
                                                u16* __restrict__ kt,
                                                u16* __restrict__ vv) {
  const int nblk = blockIdx.x, mblk = blockIdx.y, b = blockIdx.z;
  const int tid = threadIdx.x;
  const int w = tid >> 6, l = tid & 63, quad = l >> 4, col = l & 15;
  const int m0 = mblk * 64 + w * 16;
  const int n0 = nblk * 64;
  const u16* xb = xnT + b * (kN * kC);
  f32x4 acc[4] = {{0,0,0,0},{0,0,0,0},{0,0,0,0},{0,0,0,0}};
  const u16* ap = qkvw + (m0 + col) * kC + quad * 8;
  const u16* bp = xb + (n0 + col) * kC + quad * 8;
#pragma unroll
  for (int ks = 0; ks < 8; ++ks) {
    const bf16x8 af = ldb8(ap + ks * 32);
#pragma unroll
    for (int nt = 0; nt < 4; ++nt) {
      const bf16x8 bfr = ldb8(bp + nt * (16 * kC) + ks * 32);
      acc[nt] = MFMA16x16x32(af, bfr, acc[nt]);
    }
  }
  const int o_base = m0 + quad * 4;
  const int head = o_base / 192;
  const int rr = o_base % 192;
  const int bh = b * kHeads + head;
  const int seg = rr >> 6;
  const int c0 = rr & 63;
  float bias[4];
#pragma unroll
  for (int r = 0; r < 4; ++r) bias[r] = qkvb[o_base + r];
  const float sc = (seg == 0) ? kScaleQ : kScale;
#pragma unroll
  for (int nt = 0; nt < 4; ++nt) {
    const int t = n0 + nt * 16 + col;
    if (seg == 2) {
      // permuted position within the 32-block (see header comment)
      const int tp = n0 + (nt >> 1) * 32 + 2 * col + (nt & 1);
#pragma unroll
      for (int r = 0; r < 4; ++r)
        vv[bh * (kD * kN) + (c0 + r) * kN + tp] = f2bf(acc[nt][r] + bias[r]);
    } else {
      u16* dst = (seg == 0 ? qt : kt) + bh * (kN * kD) + t * kD + c0;
      u16x4 pk;
#pragma unroll
      for (int r = 0; r < 4; ++r) pk[r] = f2bf((acc[nt][r] + bias[r]) * sc);
      *reinterpret_cast<u16x4*>(dst) = pk;
    }
  }
}

// ---------------------------------------------------------------------------
// Flash attention, linear split form, 64 Q-rows/wave (4 Q-tiles).
// r14: P written to LDS as u32 pairs (p_c, p_{c+16}) via one v_perm_b32
// (RTZ bf16) -> 16 ds_write_b32 + 16 perms per iter instead of
// 32 ds_write_b16 + ~160 VALU ops. s-order permutation matches vv layout.
// r15: counters showed OccupancyPercent=21.5 => only 2 waves/SIMD resident
// (92 arch VGPR + 80 acc = 172 -> granule 176 -> floor(512/176)=2).
// Changes: launch_bounds(256,3) to force <=168 unified regs; exp2f instead of
// exp (log2e folded into Q scale, saves 32 v_mul/iter; exp2f lowers to the
// native v_exp_f32 which IS 2^x); V loads moved to just before the lgkm
// drain (latency still covered, live range halved for RA).
// r16: __exp2f does not exist as a device builtin (glibc macro collision) —
// use plain exp2f().
// ---------------------------------------------------------------------------
__global__ __launch_bounds__(256, 3) void attn_split(const u16* __restrict__ qt,
                                                     const u16* __restrict__ kt,
                                                     const u16* __restrict__ vv,
                                                     float* __restrict__ pO,
                                                     float* __restrict__ pl) {
  const int tblk = blockIdx.x, bh = blockIdx.y, z = blockIdx.z;
  const int tid = threadIdx.x;
  const int w = tid >> 6, l = tid & 63, quad = l >> 4, col = l & 15;
  const int t0 = tblk * 256 + w * 64;
  const u16* qb = qt + bh * (kN * kD);
  const u16* kb = kt + bh * (kN * kD);
  const u16* vb = vv + bh * (kD * kN);
  bf16x8 qf[4][2];
#pragma unroll
  for (int ti = 0; ti < 4; ++ti) {
    qf[ti][0] = ldb8(qb + (t0 + ti * 16 + col) * kD + quad * 8);
    qf[ti][1] = ldb8(qb + (t0 + ti * 16 + col) * kD + 32 + quad * 8);
  }
  u16x8 ones_u;
#pragma unroll
  for (int i = 0; i < 8; ++i) ones_u[i] = 0x3f80;  // bf16 1.0
  const bf16x8 onesf = *reinterpret_cast<bf16x8*>(&ones_u);
  f32x4 oacc[4][4];
  f32x4 lacc[4];
#pragma unroll
  for (int ti = 0; ti < 4; ++ti) {
    lacc[ti] = f32x4{0, 0, 0, 0};
#pragma unroll
    for (int ct = 0; ct < 4; ++ct) oacc[ti][ct] = f32x4{0, 0, 0, 0};
  }
  __shared__ __align__(16) u16 pbuf[4][4][16][36];  // 18432 B, row stride 72 B
  const int s_beg = z * (kN / kSplit);

  for (int ii = 0; ii < kN / kSplit; ii += 32) {
    const int s0 = s_beg + ii;
    const u16* kr = kb + s0 * kD + quad * 8;
    const bf16x8 k00 = ldb8(kr + col * kD);
    const bf16x8 k01 = ldb8(kr + col * kD + 32);
    const bf16x8 k10 = ldb8(kr + (col + 16) * kD);
    const bf16x8 k11 = ldb8(kr + (col + 16) * kD + 32);
    u16(*pw)[16][36] = pbuf[w];
#pragma unroll
    for (int ti = 0; ti < 4; ++ti) {
      f32x4 sa0 = {0, 0, 0, 0}, sa1 = {0, 0, 0, 0};
      sa0 = MFMA16x16x32(qf[ti][0], k00, sa0);
      sa0 = MFMA16x16x32(qf[ti][1], k01, sa0);
      sa1 = MFMA16x16x32(qf[ti][0], k10, sa1);
      sa1 = MFMA16x16x32(qf[ti][1], k11, sa1);
#pragma unroll
      for (int r = 0; r < 4; ++r) {
        const u32 e0 = __float_as_uint(exp2f(sa0[r]));
        const u32 e1 = __float_as_uint(exp2f(sa1[r]));
        // one v_perm: low16 = bf16_rtz(e0) [s=col], high16 = bf16_rtz(e1) [s=col+16]
        const u32 pk = __builtin_amdgcn_perm(e1, e0, 0x07060302u);
        *reinterpret_cast<u32*>(&pw[ti][quad * 4 + r][2 * col]) = pk;
      }
    }
    // V fragment loads issued here (r15): their latency overlaps the DS drain
    // below, and the shorter live range frees registers for 3 waves/SIMD.
    const u16* vr = vb + s0 + quad * 8;
    bf16x8 vf[4];
#pragma unroll
    for (int ct = 0; ct < 4; ++ct) vf[ct] = ldb8(vr + (ct * 16 + col) * kN);
    // wave-private LDS region: drain writes, then read A-layout fragments.
    // DS is in-order per wave, so next-iter writes cannot bypass these reads.
    asm volatile("s_waitcnt lgkmcnt(0)" ::: "memory");
#pragma unroll
    for (int ti = 0; ti < 4; ++ti) {
      const bf16x8 pf = ldb8(&pw[ti][col][quad * 8]);
#pragma unroll
      for (int ct = 0; ct < 4; ++ct)
        oacc[ti][ct] = MFMA16x16x32(pf, vf[ct], oacc[ti][ct]);
      lacc[ti] = MFMA16x16x32(pf, onesf, lacc[ti]);
    }
  }
  float* po = pO + (size_t)(z * 16 + bh) * kN * kD;
  float* plp = pl + (size_t)(z * 16 + bh) * kN;
#pragma unroll
  for (int ti = 0; ti < 4; ++ti)
#pragma unroll
    for (int r = 0; r < 4; ++r) {
      const int t = t0 + ti * 16 + quad * 4 + r;
#pragma unroll
      for (int ct = 0; ct < 4; ++ct)
        po[(size_t)t * kD + ct * 16 + col] = oacc[ti][ct][r];
      if (col == 0) plp[t] = lacc[ti][r];
    }
}

// ---------------------------------------------------------------------------
// Combine 4 split partials: O = sum_z O_z / sum_z l_z -> ht[b][t][c] bf16.
// ---------------------------------------------------------------------------
__global__ __launch_bounds__(256) void attn_combine(const float* __restrict__ pO,
                                                    const float* __restrict__ pl,
                                                    u16* __restrict__ ht) {
  const int idx = blockIdx.x * 256 + threadIdx.x;   // 16bh * 4096t * 16chunks
  const int c0 = (idx & 15) * 4;
  const int t = (idx >> 4) & (kN - 1);
  const int bh = idx >> 16;
  f32x4 acc = {0, 0, 0, 0};
  float lsum = 0.f;
#pragma unroll
  for (int z = 0; z < kSplit; ++z) {
    const size_t base = ((size_t)(z * 16 + bh) * kN + t);
    acc += *reinterpret_cast<const f32x4*>(pO + base * kD + c0);
    lsum += pl[base];
  }
  const float inv = 1.f / lsum;
  u16x4 pk;
#pragma unroll
  for (int i = 0; i < 4; ++i) pk[i] = f2bf(acc[i] * inv);
  const int b = bh >> 2, head = bh & 3;
  *reinterpret_cast<u16x4*>(ht + (size_t)b * (kN * kC) + (size_t)t * kC +
                            head * kD + c0) = pk;
}

// ---------------------------------------------------------------------------
// Proj GEMM + bias + residual: out fp32 (B,C,H,W). Validated r6.
// ---------------------------------------------------------------------------
__global__ __launch_bounds__(256) void proj_kernel(const u16* __restrict__ projw,
                                                   const float* __restrict__ projb,
                                                   const u16* __restrict__ ht,
                                                   const float* __restrict__ x,
                                                   float* __restrict__ out) {
  const int nblk = blockIdx.x, mblk = blockIdx.y, b = blockIdx.z;
  const int tid = threadIdx.x;
  const int w = tid >> 6, l = tid & 63, quad = l >> 4, col = l & 15;
  const int m0 = mblk * 64 + w * 16;
  const int n0 = nblk * 64;
  const u16* hb = ht + b * (kN * kC);
  f32x4 acc[4] = {{0,0,0,0},{0,0,0,0},{0,0,0,0},{0,0,0,0}};
  const u16* ap = projw + (m0 + col) * kC + quad * 8;
  const u16* bp = hb + (n0 + col) * kC + quad * 8;
#pragma unroll
  for (int ks = 0; ks < 8; ++ks) {
    const bf16x8 af = ldb8(ap + ks * 32);
#pragma unroll
    for (int nt = 0; nt < 4; ++nt) {
      const bf16x8 bfr = ldb8(bp + nt * (16 * kC) + ks * 32);
      acc[nt] = MFMA16x16x32(af, bfr, acc[nt]);
    }
  }
#pragma unroll
  for (int nt = 0; nt < 4; ++nt) {
    const int t = n0 + nt * 16 + col;
#pragma unroll
    for (int r = 0; r < 4; ++r) {
      const int o = m0 + quad * 4 + r;
      const int idx = b * (kC * kN) + o * kN + t;
      out[idx] = acc[nt][r] + projb[o] + x[idx];
    }
  }
}

extern "C" void kernel_launch(void* const* d_in, const int* in_sizes, int n_in,
                              void* d_out, int out_size, void* d_ws, size_t ws_size,
                              hipStream_t stream) {
  const float* x = (const float*)d_in[0];
  const float* gnw = (const float*)d_in[1];
  const float* gnb = (const float*)d_in[2];
  const float* qkvw_f = (const float*)d_in[3];
  const float* qkvb = (const float*)d_in[4];
  const float* projw_f = (const float*)d_in[5];
  const float* projb = (const float*)d_in[6];
  float* out = (float*)d_out;

  char* ws = (char*)d_ws;
  u16* xnT = (u16*)(ws);                      // 8 MiB
  u16* qt = (u16*)(ws + (8u << 20));          // 8 MiB
  u16* kt = (u16*)(ws + (16u << 20));         // 8 MiB
  u16* vv = (u16*)(ws + (24u << 20));         // 8 MiB
  u16* ht = (u16*)(ws + (32u << 20));         // 8 MiB
  u16* qkvw = (u16*)(ws + (40u << 20));       // 384 KiB
  u16* projw = (u16*)(ws + (41u << 20));      // 128 KiB
  float* pO = (float*)(ws + (48u << 20));     // 64 MiB (4 splits)
  float* pl = (float*)(ws + (112u << 20));    // 1 MiB

  convert_bf16<<<dim3(192), dim3(256), 0, stream>>>(qkvw_f, qkvw, 768 * kC);
  convert_bf16<<<dim3(64), dim3(256), 0, stream>>>(projw_f, projw, kC * kC);
  gn_kernel<<<dim3(32, 4), dim3(1024), 0, stream>>>(x, gnw, gnb, xnT);
  qkv_gemm<<<dim3(64, 12, 4), dim3(256), 0, stream>>>(qkvw, qkvb, xnT, qt, kt, vv);
  attn_split<<<dim3(16, 16, kSplit), dim3(256), 0, stream>>>(qt, kt, vv, pO, pl);
  attn_combine<<<dim3(4096), dim3(256), 0, stream>>>(pO, pl, ht);
  proj_kernel<<<dim3(64, 4, 4), dim3(256), 0, stream>>>(projw, projb, ht, x, out);
}

// Round 3
// 312.330 us; speedup vs baseline: 1.0471x; 1.0471x over previous
//
#include <hip/hip_runtime.h>

typedef unsigned short u16;
typedef unsigned int u32;
typedef __bf16 bf16x8 __attribute__((ext_vector_type(8)));
typedef float f32x4 __attribute__((ext_vector_type(4)));
typedef u16 u16x4 __attribute__((ext_vector_type(4)));
typedef u16 u16x8 __attribute__((ext_vector_type(8)));

#define MFMA16x16x32(a, b, c) __builtin_amdgcn_mfma_f32_16x16x32_bf16((a), (b), (c), 0, 0, 0)

static constexpr int kB = 4;
static constexpr int kC = 256;
static constexpr int kN = 4096;     // H*W
static constexpr int kHeads = 4;    // per batch
static constexpr int kD = 64;       // head dim
static constexpr int kSplit = 4;    // attn is reg-capped, not grid-capped; 4 halves combine traffic
static constexpr float kScale = 0.35355339059327373f;   // 64^-0.25 (K side)
static constexpr float kScaleQ = 0.51006971545f;        // 64^-0.25 * log2(e) (Q side, r15: exp->exp2)

__device__ __forceinline__ u16 f2bf(float f) {
  union { float f; u32 i; } v; v.f = f;
  return (u16)((v.i + 0x7fffu + ((v.i >> 16) & 1u)) >> 16);
}
__device__ __forceinline__ bf16x8 ldb8(const u16* p) {
  return *reinterpret_cast<const bf16x8*>(p);
}

// ---------------------------------------------------------------------------
// fp32 -> bf16 weight conversion (grid-stride).
// ---------------------------------------------------------------------------
__global__ void convert_bf16(const float* __restrict__ in, u16* __restrict__ out,
                             int n) {
  for (int i = blockIdx.x * blockDim.x + threadIdx.x; i < n;
       i += gridDim.x * blockDim.x)
    out[i] = f2bf(in[i]);
}

// ---------------------------------------------------------------------------
// GroupNorm (validated r4). Writes bf16 transposed xnT[b][t][c].
// ---------------------------------------------------------------------------
__global__ __launch_bounds__(1024) void gn_kernel(const float* __restrict__ x,
                                                  const float* __restrict__ gnw,
                                                  const float* __restrict__ gnb,
                                                  u16* __restrict__ xnT) {
  const int g = blockIdx.x, b = blockIdx.y;
  const int tid = threadIdx.x;
  const float* xb = x + b * (kC * kN) + g * 8 * kN;
  float vals[4][8];
  float s = 0.f, ss = 0.f;
#pragma unroll
  for (int kk = 0; kk < 4; ++kk) {
    const int t = tid + kk * 1024;
#pragma unroll
    for (int c = 0; c < 8; ++c) {
      const float v_ = xb[c * kN + t];
      vals[kk][c] = v_;
      s += v_; ss += v_ * v_;
    }
  }
#pragma unroll
  for (int off = 32; off > 0; off >>= 1) {
    s += __shfl_down(s, off);
    ss += __shfl_down(ss, off);
  }
  __shared__ float rbuf[32];
  const int wid = tid >> 6, lane = tid & 63;
  if (lane == 0) { rbuf[wid] = s; rbuf[16 + wid] = ss; }
  __syncthreads();
  if (tid < 64) {
    float s2 = (lane < 16) ? rbuf[lane] : 0.f;
    float ss2 = (lane < 16) ? rbuf[16 + lane] : 0.f;
#pragma unroll
    for (int off = 8; off > 0; off >>= 1) {
      s2 += __shfl_down(s2, off);
      ss2 += __shfl_down(ss2, off);
    }
    if (lane == 0) { rbuf[0] = s2; rbuf[1] = ss2; }
  }
  __syncthreads();
  const float inv_n = 1.f / 32768.f;
  const float mu = rbuf[0] * inv_n;
  const float var = rbuf[1] * inv_n - mu * mu;
  const float rs = rsqrtf(var + 1e-5f);
  float wv[8], bv[8];
#pragma unroll
  for (int c = 0; c < 8; ++c) {
    const float wgt = gnw[g * 8 + c] * rs;
    wv[c] = wgt;
    bv[c] = gnb[g * 8 + c] - mu * wgt;
  }
  u16* ob = xnT + b * (kN * kC) + g * 8;
#pragma unroll
  for (int kk = 0; kk < 4; ++kk) {
    const int t = tid + kk * 1024;
    u16x8 pk;
#pragma unroll
    for (int c = 0; c < 8; ++c) pk[c] = f2bf(vals[kk][c] * wv[c] + bv[c]);
    *reinterpret_cast<u16x8*>(ob + t * kC) = pk;
  }
}

// ---------------------------------------------------------------------------
// QKV GEMM (validated r4). Epilogue: qT/kT[bh][t][64] pre-scaled.
// r14: V stored PERMUTED within each 32-column block: stored index
// 2c <-> s=c, 2c+1 <-> s=c+16. Matches attn's packed-P LDS ordering
// (MFMA k-order is summation order -> exact as long as P and V agree).
// r15: Q side additionally folds log2(e) so attn uses exp2 directly.
// ---------------------------------------------------------------------------
__global__ __launch_bounds__(256) void qkv_gemm(const u16* __restrict__ qkvw,
                                                const float* __restrict__ qkvb,
                                                const u16* __restrict__ xnT,
                                                u16* __restrict__ qt,
                                                u16* __restrict__ kt,
                                                u16* __restrict__ vv) {
  const int nblk = blockIdx.x, mblk = blockIdx.y, b = blockIdx.z;
  const int tid = threadIdx.x;
  const int w = tid >> 6, l = tid & 63, quad = l >> 4, col = l & 15;
  const int m0 = mblk * 64 + w * 16;
  const int n0 = nblk * 64;
  const u16* xb = xnT + b * (kN * kC);
  f32x4 acc[4] = {{0,0,0,0},{0,0,0,0},{0,0,0,0},{0,0,0,0}};
  const u16* ap = qkvw + (m0 + col) * kC + quad * 8;
  const u16* bp = xb + (n0 + col) * kC + quad * 8;
#pragma unroll
  for (int ks = 0; ks < 8; ++ks) {
    const bf16x8 af = ldb8(ap + ks * 32);
#pragma unroll
    for (int nt = 0; nt < 4; ++nt) {
      const bf16x8 bfr = ldb8(bp + nt * (16 * kC) + ks * 32);
      acc[nt] = MFMA16x16x32(af, bfr, acc[nt]);
    }
  }
  const int o_base = m0 + quad * 4;
  const int head = o_base / 192;
  const int rr = o_base % 192;
  const int bh = b * kHeads + head;
  const int seg = rr >> 6;
  const int c0 = rr & 63;
  float bias[4];
#pragma unroll
  for (int r = 0; r < 4; ++r) bias[r] = qkvb[o_base + r];
  const float sc = (seg == 0) ? kScaleQ : kScale;
#pragma unroll
  for (int nt = 0; nt < 4; ++nt) {
    const int t = n0 + nt * 16 + col;
    if (seg == 2) {
      // permuted position within the 32-block (see header comment)
      const int tp = n0 + (nt >> 1) * 32 + 2 * col + (nt & 1);
#pragma unroll
      for (int r = 0; r < 4; ++r)
        vv[bh * (kD * kN) + (c0 + r) * kN + tp] = f2bf(acc[nt][r] + bias[r]);
    } else {
      u16* dst = (seg == 0 ? qt : kt) + bh * (kN * kD) + t * kD + c0;
      u16x4 pk;
#pragma unroll
      for (int r = 0; r < 4; ++r) pk[r] = f2bf((acc[nt][r] + bias[r]) * sc);
      *reinterpret_cast<u16x4*>(dst) = pk;
    }
  }
}

// ---------------------------------------------------------------------------
// Flash attention, linear split form, 64 Q-rows/wave (4 Q-tiles).
// r14: P written to LDS as u32 pairs (p_c, p_{c+16}) via one v_perm_b32.
// r15: exp2f with log2e folded into Q scale (kept).
// r16 POST-MORTEM: launch_bounds(256,3) regressed 140->170us. VALUBusy
// 25->38 with VGPR capped at 80: allocator met the bound with accvgpr
// shuffles/remat, occupancy only 21.5->24. Occupancy can't be bought here.
// r17: back to (256,2); hide the latency instead. K/V for tile ii+32 are
// prefetched into a second register set at loop top (wrap-indexed so the
// last prefetch is a valid dummy), consumed one iteration later. +32 VGPR
// staging (~204 unified/wave, fine at 2 waves/SIMD budget of 256).
// ---------------------------------------------------------------------------
__global__ __launch_bounds__(256, 2) void attn_split(const u16* __restrict__ qt,
                                                     const u16* __restrict__ kt,
                                                     const u16* __restrict__ vv,
                                                     float* __restrict__ pO,
                                                     float* __restrict__ pl) {
  const int tblk = blockIdx.x, bh = blockIdx.y, z = blockIdx.z;
  const int tid = threadIdx.x;
  const int w = tid >> 6, l = tid & 63, quad = l >> 4, col = l & 15;
  const int t0 = tblk * 256 + w * 64;
  const u16* qb = qt + bh * (kN * kD);
  const u16* kb = kt + bh * (kN * kD);
  const u16* vb = vv + bh * (kD * kN);
  bf16x8 qf[4][2];
#pragma unroll
  for (int ti = 0; ti < 4; ++ti) {
    qf[ti][0] = ldb8(qb + (t0 + ti * 16 + col) * kD + quad * 8);
    qf[ti][1] = ldb8(qb + (t0 + ti * 16 + col) * kD + 32 + quad * 8);
  }
  u16x8 ones_u;
#pragma unroll
  for (int i = 0; i < 8; ++i) ones_u[i] = 0x3f80;  // bf16 1.0
  const bf16x8 onesf = *reinterpret_cast<bf16x8*>(&ones_u);
  f32x4 oacc[4][4];
  f32x4 lacc[4];
#pragma unroll
  for (int ti = 0; ti < 4; ++ti) {
    lacc[ti] = f32x4{0, 0, 0, 0};
#pragma unroll
    for (int ct = 0; ct < 4; ++ct) oacc[ti][ct] = f32x4{0, 0, 0, 0};
  }
  __shared__ __align__(16) u16 pbuf[4][4][16][36];  // 18432 B, row stride 72 B
  constexpr int NS = kN / kSplit;  // 1024
  const int s_beg = z * NS;

  // --- prefetch tile 0 (current set) ---
  const u16* kr0 = kb + s_beg * kD + quad * 8;
  bf16x8 k00 = ldb8(kr0 + col * kD);
  bf16x8 k01 = ldb8(kr0 + col * kD + 32);
  bf16x8 k10 = ldb8(kr0 + (col + 16) * kD);
  bf16x8 k11 = ldb8(kr0 + (col + 16) * kD + 32);
  const u16* vr0 = vb + s_beg + quad * 8;
  bf16x8 vf0 = ldb8(vr0 + (0 * 16 + col) * kN);
  bf16x8 vf1 = ldb8(vr0 + (1 * 16 + col) * kN);
  bf16x8 vf2 = ldb8(vr0 + (2 * 16 + col) * kN);
  bf16x8 vf3 = ldb8(vr0 + (3 * 16 + col) * kN);

#pragma unroll 2
  for (int ii = 0; ii < NS; ii += 32) {
    // --- issue next-tile loads first (consumed next iteration; wrap makes
    // the final prefetch a valid, discarded load) ---
    const int sn = s_beg + ((ii + 32) & (NS - 1));
    const u16* krn = kb + sn * kD + quad * 8;
    const bf16x8 n00 = ldb8(krn + col * kD);
    const bf16x8 n01 = ldb8(krn + col * kD + 32);
    const bf16x8 n10 = ldb8(krn + (col + 16) * kD);
    const bf16x8 n11 = ldb8(krn + (col + 16) * kD + 32);
    const u16* vrn = vb + sn + quad * 8;
    const bf16x8 m0 = ldb8(vrn + (0 * 16 + col) * kN);
    const bf16x8 m1 = ldb8(vrn + (1 * 16 + col) * kN);
    const bf16x8 m2 = ldb8(vrn + (2 * 16 + col) * kN);
    const bf16x8 m3 = ldb8(vrn + (3 * 16 + col) * kN);

    u16(*pw)[16][36] = pbuf[w];
#pragma unroll
    for (int ti = 0; ti < 4; ++ti) {
      f32x4 sa0 = {0, 0, 0, 0}, sa1 = {0, 0, 0, 0};
      sa0 = MFMA16x16x32(qf[ti][0], k00, sa0);
      sa0 = MFMA16x16x32(qf[ti][1], k01, sa0);
      sa1 = MFMA16x16x32(qf[ti][0], k10, sa1);
      sa1 = MFMA16x16x32(qf[ti][1], k11, sa1);
#pragma unroll
      for (int r = 0; r < 4; ++r) {
        const u32 e0 = __float_as_uint(exp2f(sa0[r]));
        const u32 e1 = __float_as_uint(exp2f(sa1[r]));
        // one v_perm: low16 = bf16_rtz(e0) [s=col], high16 = bf16_rtz(e1) [s=col+16]
        const u32 pk = __builtin_amdgcn_perm(e1, e0, 0x07060302u);
        *reinterpret_cast<u32*>(&pw[ti][quad * 4 + r][2 * col]) = pk;
      }
    }
    // wave-private LDS region: drain writes, then read A-layout fragments.
    // DS is in-order per wave, so next-iter writes cannot bypass these reads.
    asm volatile("s_waitcnt lgkmcnt(0)" ::: "memory");
#pragma unroll
    for (int ti = 0; ti < 4; ++ti) {
      const bf16x8 pf = ldb8(&pw[ti][col][quad * 8]);
      oacc[ti][0] = MFMA16x16x32(pf, vf0, oacc[ti][0]);
      oacc[ti][1] = MFMA16x16x32(pf, vf1, oacc[ti][1]);
      oacc[ti][2] = MFMA16x16x32(pf, vf2, oacc[ti][2]);
      oacc[ti][3] = MFMA16x16x32(pf, vf3, oacc[ti][3]);
      lacc[ti] = MFMA16x16x32(pf, onesf, lacc[ti]);
    }
    // rotate prefetched registers into current set
    k00 = n00; k01 = n01; k10 = n10; k11 = n11;
    vf0 = m0; vf1 = m1; vf2 = m2; vf3 = m3;
  }
  float* po = pO + (size_t)(z * 16 + bh) * kN * kD;
  float* plp = pl + (size_t)(z * 16 + bh) * kN;
#pragma unroll
  for (int ti = 0; ti < 4; ++ti)
#pragma unroll
    for (int r = 0; r < 4; ++r) {
      const int t = t0 + ti * 16 + quad * 4 + r;
#pragma unroll
      for (int ct = 0; ct < 4; ++ct)
        po[(size_t)t * kD + ct * 16 + col] = oacc[ti][ct][r];
      if (col == 0) plp[t] = lacc[ti][r];
    }
}

// ---------------------------------------------------------------------------
// Combine 4 split partials: O = sum_z O_z / sum_z l_z -> ht[b][t][c] bf16.
// ---------------------------------------------------------------------------
__global__ __launch_bounds__(256) void attn_combine(const float* __restrict__ pO,
                                                    const float* __restrict__ pl,
                                                    u16* __restrict__ ht) {
  const int idx = blockIdx.x * 256 + threadIdx.x;   // 16bh * 4096t * 16chunks
  const int c0 = (idx & 15) * 4;
  const int t = (idx >> 4) & (kN - 1);
  const int bh = idx >> 16;
  f32x4 acc = {0, 0, 0, 0};
  float lsum = 0.f;
#pragma unroll
  for (int z = 0; z < kSplit; ++z) {
    const size_t base = ((size_t)(z * 16 + bh) * kN + t);
    acc += *reinterpret_cast<const f32x4*>(pO + base * kD + c0);
    lsum += pl[base];
  }
  const float inv = 1.f / lsum;
  u16x4 pk;
#pragma unroll
  for (int i = 0; i < 4; ++i) pk[i] = f2bf(acc[i] * inv);
  const int b = bh >> 2, head = bh & 3;
  *reinterpret_cast<u16x4*>(ht + (size_t)b * (kN * kC) + (size_t)t * kC +
                            head * kD + c0) = pk;
}

// ---------------------------------------------------------------------------
// Proj GEMM + bias + residual: out fp32 (B,C,H,W). Validated r6.
// ---------------------------------------------------------------------------
__global__ __launch_bounds__(256) void proj_kernel(const u16* __restrict__ projw,
                                                   const float* __restrict__ projb,
                                                   const u16* __restrict__ ht,
                                                   const float* __restrict__ x,
                                                   float* __restrict__ out) {
  const int nblk = blockIdx.x, mblk = blockIdx.y, b = blockIdx.z;
  const int tid = threadIdx.x;
  const int w = tid >> 6, l = tid & 63, quad = l >> 4, col = l & 15;
  const int m0 = mblk * 64 + w * 16;
  const int n0 = nblk * 64;
  const u16* hb = ht + b * (kN * kC);
  f32x4 acc[4] = {{0,0,0,0},{0,0,0,0},{0,0,0,0},{0,0,0,0}};
  const u16* ap = projw + (m0 + col) * kC + quad * 8;
  const u16* bp = hb + (n0 + col) * kC + quad * 8;
#pragma unroll
  for (int ks = 0; ks < 8; ++ks) {
    const bf16x8 af = ldb8(ap + ks * 32);
#pragma unroll
    for (int nt = 0; nt < 4; ++nt) {
      const bf16x8 bfr = ldb8(bp + nt * (16 * kC) + ks * 32);
      acc[nt] = MFMA16x16x32(af, bfr, acc[nt]);
    }
  }
#pragma unroll
  for (int nt = 0; nt < 4; ++nt) {
    const int t = n0 + nt * 16 + col;
#pragma unroll
    for (int r = 0; r < 4; ++r) {
      const int o = m0 + quad * 4 + r;
      const int idx = b * (kC * kN) + o * kN + t;
      out[idx] = acc[nt][r] + projb[o] + x[idx];
    }
  }
}

extern "C" void kernel_launch(void* const* d_in, const int* in_sizes, int n_in,
                              void* d_out, int out_size, void* d_ws, size_t ws_size,
                              hipStream_t stream) {
  const float* x = (const float*)d_in[0];
  const float* gnw = (const float*)d_in[1];
  const float* gnb = (const float*)d_in[2];
  const float* qkvw_f = (const float*)d_in[3];
  const float* qkvb = (const float*)d_in[4];
  const float* projw_f = (const float*)d_in[5];
  const float* projb = (const float*)d_in[6];
  float* out = (float*)d_out;

  char* ws = (char*)d_ws;
  u16* xnT = (u16*)(ws);                      // 8 MiB
  u16* qt = (u16*)(ws + (8u << 20));          // 8 MiB
  u16* kt = (u16*)(ws + (16u << 20));         // 8 MiB
  u16* vv = (u16*)(ws + (24u << 20));         // 8 MiB
  u16* ht = (u16*)(ws + (32u << 20));         // 8 MiB
  u16* qkvw = (u16*)(ws + (40u << 20));       // 384 KiB
  u16* projw = (u16*)(ws + (41u << 20));      // 128 KiB
  float* pO = (float*)(ws + (48u << 20));     // 64 MiB (4 splits)
  float* pl = (float*)(ws + (112u << 20));    // 1 MiB

  convert_bf16<<<dim3(192), dim3(256), 0, stream>>>(qkvw_f, qkvw, 768 * kC);
  convert_bf16<<<dim3(64), dim3(256), 0, stream>>>(projw_f, projw, kC * kC);
  gn_kernel<<<dim3(32, 4), dim3(1024), 0, stream>>>(x, gnw, gnb, xnT);
  qkv_gemm<<<dim3(64, 12, 4), dim3(256), 0, stream>>>(qkvw, qkvb, xnT, qt, kt, vv);
  attn_split<<<dim3(16, 16, kSplit), dim3(256), 0, stream>>>(qt, kt, vv, pO, pl);
  attn_combine<<<dim3(4096), dim3(256), 0, stream>>>(pO, pl, ht);
  proj_kernel<<<dim3(64, 4, 4), dim3(256), 0, stream>>>(projw, projb, ht, x, out);
}